// Round 13
// baseline (178.638 us; speedup 1.0000x reference)
//
#include <hip/hip_runtime.h>

namespace {

constexpr int NQ = 12;
constexpr int NL = 3;
constexpr int FEAT = 64;
constexpr float PI_F = 3.14159265358979323846f;

typedef float f2 __attribute__((ext_vector_type(2)));

// ============================ constexpr GF(2) toolkit ============================
constexpr int par12(unsigned x) { int p = 0; for (int i = 0; i < 12; ++i) p ^= (int)((x >> i) & 1u); return p; }
constexpr int lead12(unsigned x) { for (int k = 11; k >= 0; --k) if ((x >> k) & 1u) return k; return -1; }

struct Ech { unsigned v[16] = {}; int n = 0; };
constexpr unsigned ech_reduce(const Ech& E, unsigned x) {
  for (int i = 0; i < E.n; ++i) { int lb = lead12(E.v[i]); if (lb >= 0 && ((x >> lb) & 1u)) x ^= E.v[i]; }
  return x;
}
constexpr bool ech_add(Ech& E, unsigned x) {
  unsigned r = ech_reduce(E, x);
  if (!r) return false;
  int lb = lead12(r);
  int pos = E.n;
  for (int i = 0; i < E.n; ++i) { if (lead12(E.v[i]) < lb) { pos = i; break; } }
  for (int i = E.n; i > pos; --i) E.v[i] = E.v[i - 1];
  E.v[pos] = r; E.n++;
  return true;
}

constexpr unsigned apmat(const unsigned* rows, unsigned v) {
  unsigned o = 0; for (int k = 0; k < 12; ++k) if (par12(rows[k] & v)) o |= 1u << k; return o;
}
constexpr bool inv12(const unsigned* in, unsigned* out) {
  unsigned a[12] = {}, b[12] = {};
  for (int k = 0; k < 12; ++k) { a[k] = in[k]; b[k] = 1u << k; }
  for (int c = 0; c < 12; ++c) {
    int p = -1;
    for (int r = c; r < 12; ++r) if ((a[r] >> c) & 1u) { p = r; break; }
    if (p < 0) return false;
    unsigned t = a[c]; a[c] = a[p]; a[p] = t; t = b[c]; b[c] = b[p]; b[p] = t;
    for (int r = 0; r < 12; ++r) if (r != c && ((a[r] >> c) & 1u)) { a[r] ^= a[c]; b[r] ^= b[c]; }
  }
  for (int k = 0; k < 12; ++k) out[k] = b[k];
  return true;
}
constexpr unsigned dropb(unsigned x, int t) {
  unsigned lm = (1u << t) - 1u;
  return (x & lm) | ((x >> 1) & (0x7FFu & ~lm));
}

// ============ logical circuit tracking (deferred CNOT ring, verified r1-r11) ============
struct Logical {
  unsigned m[NL][NQ] = {}, rv[NL][NQ] = {}, rf[NQ] = {};
  bool ok = false;
};
constexpr Logical compute_raw() {
  Logical mp{};
  unsigned col[NQ] = {}, row[NQ] = {};
  for (int b = 0; b < NQ; ++b) { col[b] = 1u << b; row[b] = 1u << b; }
  mp.ok = true;
  for (int L = 0; L < NL; ++L) {
    for (int q = 0; q < NQ; ++q) {
      mp.m[L][q]  = col[NQ - 1 - q];
      mp.rv[L][q] = row[NQ - 1 - q];
      if (par12(mp.m[L][q] & mp.rv[L][q]) != 1) mp.ok = false;
    }
    for (int q = 0; q < NQ; ++q) {
      int bc = NQ - 1 - q;
      int bt = NQ - 1 - ((q + 1) % NQ);
      col[bc] ^= col[bt];
      row[bt] ^= row[bc];
    }
  }
  for (int q = 0; q < NQ; ++q) mp.rf[q] = row[NQ - 1 - q];
  return mp;
}

// ============================ phase/remap plan (VERIFIED in r10/r11) ============================
// Storage index p: bits [0..5] lane, bits [6..11] reg. Reg bit 5 (storage bit 11) is the
// WAVE BIT at runtime: wave w owns {r: bit5(r) = w}, 32 f2 (64 VGPR) per lane.
struct Plan {
  unsigned l0m[NQ] = {}, l0r[NQ] = {};
  unsigned gm[4][6] = {};      // storage masks (reg-local: low 6 bits zero)
  unsigned gr[4][6] = {};      // storage parity rows
  unsigned rf[NQ] = {};        // final measurement parity rows
  unsigned phi[4][6] = {};     // old-storage images of new lane basis
  unsigned coffE[4][64] = {};  // per-new-reg old-entry offset (11-bit, chunk bit dropped)
  int cb[4] = {};              // chunk reg-bit (0..5)
  bool ok = false;
};

constexpr bool findH(const Ech& G, unsigned rho, unsigned& out) {
  for (unsigned t = 0; t < 12; ++t) {
    unsigned v = 1u << t;
    if (par12(v & rho) == 0 && ech_reduce(G, v)) { out = v; return true; }
  }
  for (unsigned v = 1; v < 4096u; ++v) {
    if (par12(v & rho) == 0 && ech_reduce(G, v)) { out = v; return true; }
  }
  return false;
}

constexpr Plan build_plan() {
  Logical raw = compute_raw();
  Plan P{};
  P.ok = raw.ok;
  for (int q = 0; q < NQ; ++q) { P.l0m[q] = raw.m[0][q]; P.l0r[q] = raw.rv[0][q]; }
  unsigned fwd[12] = {}, invc[12] = {};
  for (int k = 0; k < 12; ++k) { fwd[k] = 1u << k; invc[k] = 1u << k; }
  for (int ph = 0; ph < 4; ++ph) {
    const int L = 1 + ph / 2, q0 = (ph % 2) * 6;
    unsigned ml[6] = {};
    for (int i = 0; i < 6; ++i) ml[i] = raw.m[L][q0 + i];
    bool done = false;
    for (int cbi = 5; cbi >= 0 && !done; --cbi) {
      unsigned rho = fwd[6 + cbi];
      bool bad = false;
      int idx = -1;
      for (int i = 0; i < 6; ++i) if (par12(ml[i] & rho)) { idx = i; break; }
      unsigned uc = 0;
      Ech W{};
      if (idx >= 0) {
        uc = ml[idx];
        for (int i = 0; i < 6; ++i) {
          if (i == idx) continue;
          unsigned w = par12(ml[i] & rho) ? (ml[i] ^ uc) : ml[i];
          ech_add(W, w);
        }
        if (W.n > 5) bad = true;
      } else {
        for (int i = 0; i < 6; ++i) ech_add(W, ml[i]);
        if (W.n > 5) bad = true;
        if (!bad) {
          bool got = false;
          for (unsigned t = 0; t < 12 && !got; ++t) {
            unsigned v = 1u << t;
            if (par12(v & rho)) { uc = v; got = true; }
          }
          if (!got) bad = true;
        }
      }
      if (bad) continue;
      Ech G{};
      for (int i = 0; i < W.n && !bad; ++i) if (!ech_add(G, W.v[i])) bad = true;
      if (!bad && !ech_add(G, uc)) bad = true;
      if (bad) continue;
      unsigned regH[5] = {};
      int nH = W.n;
      for (int i = 0; i < nH; ++i) regH[i] = W.v[i];
      for (int slot = nH; slot < 5 && !bad; ++slot) {
        unsigned v = 0;
        if (!findH(G, rho, v)) { bad = true; break; }
        regH[slot] = v; ech_add(G, v);
      }
      if (bad) continue;
      unsigned lam[6] = {};
      for (int j = 0; j < 6 && !bad; ++j) {
        unsigned cand = invc[j];
        if (par12(cand & rho) != 0 || !ech_reduce(G, cand)) {
          if (!findH(G, rho, cand)) { bad = true; break; }
        }
        lam[j] = cand; ech_add(G, cand);
      }
      if (bad) continue;
      unsigned ncols[12] = {};
      for (int j = 0; j < 6; ++j) ncols[j] = lam[j];
      {
        int w = 0;
        for (int k = 0; k < 6; ++k) ncols[6 + k] = (k == cbi) ? uc : regH[w++];
      }
      unsigned Mrows[12] = {};
      for (int k = 0; k < 12; ++k) {
        unsigned r = 0;
        for (int j = 0; j < 12; ++j) r |= ((ncols[j] >> k) & 1u) << j;
        Mrows[k] = r;
      }
      unsigned fnew[12] = {};
      if (!inv12(Mrows, fnew)) continue;
      bool okp = true;
      unsigned gmv[6] = {}, grv[6] = {};
      for (int i = 0; i < 6 && okp; ++i) {
        unsigned SM = apmat(fnew, ml[i]);
        if (SM & 63u) okp = false;
        unsigned sg = 0;
        for (int k = 0; k < 12; ++k) if (par12(raw.rv[L][q0 + i] & ncols[k])) sg |= 1u << k;
        if (par12(SM & sg) != 1) okp = false;
        gmv[i] = SM; grv[i] = sg;
      }
      unsigned phj[6] = {}, Ust[6] = {};
      for (int j = 0; j < 6 && okp; ++j) {
        phj[j] = apmat(fwd, lam[j]);
        if ((phj[j] >> (6 + cbi)) & 1u) okp = false;
      }
      for (int k = 0; k < 6 && okp; ++k) {
        Ust[k] = apmat(fwd, ncols[6 + k]);
        if (((Ust[k] >> (6 + cbi)) & 1u) != (unsigned)(k == cbi ? 1 : 0)) okp = false;
      }
      if (!okp) continue;
      P.cb[ph] = cbi;
      for (int j = 0; j < 6; ++j) P.phi[ph][j] = phj[j];
      for (int rp = 0; rp < 64; ++rp) {
        unsigned psi = 0;
        for (int i = 0; i < 6; ++i) if ((rp >> i) & 1) psi ^= Ust[i];
        P.coffE[ph][rp] = dropb(psi, 6 + cbi);
      }
      for (int i = 0; i < 6; ++i) { P.gm[ph][i] = gmv[i]; P.gr[ph][i] = grv[i]; }
      for (int k = 0; k < 12; ++k) { fwd[k] = fnew[k]; invc[k] = ncols[k]; }
      done = true;
    }
    if (!done) { P.ok = false; return P; }
  }
  for (int q = 0; q < NQ; ++q) {
    unsigned sg = 0;
    for (int k = 0; k < 12; ++k) if (par12(raw.rf[q] & invc[k])) sg |= 1u << k;
    P.rf[q] = sg;
  }
  return P;
}

constexpr Plan PLAN = build_plan();
static_assert(PLAN.ok, "plan construction failed");

constexpr int find_qw() { for (int q = 0; q < NQ; ++q) if (((PLAN.l0m[q] >> 6) & 63u) == 32u) return q; return -1; }
constexpr int QW = find_qw();
static_assert(QW >= 0, "no wave-bit l0 gate found");

// ============================ packed FP32 primitives (verified r4-r11) ============================
__device__ __forceinline__ f2 pk_mul_bl(f2 a, f2 u) {
  f2 d;
  asm("v_pk_mul_f32 %0, %1, %2 op_sel:[0,0] op_sel_hi:[1,0]" : "=v"(d) : "v"(a), "v"(u));
  return d;
}
__device__ __forceinline__ f2 pk_fma_rot_p(f2 a, f2 u, f2 c) {
  f2 d;
  asm("v_pk_fma_f32 %0, %1, %2, %3 op_sel:[1,1,0] op_sel_hi:[0,1,1] neg_lo:[1,0,0]"
      : "=v"(d) : "v"(a), "v"(u), "v"(c));
  return d;
}
__device__ __forceinline__ f2 pk_fma_rot_m(f2 a, f2 u, f2 c) {
  f2 d;
  asm("v_pk_fma_f32 %0, %1, %2, %3 op_sel:[1,1,0] op_sel_hi:[0,1,1] neg_hi:[1,0,0]"
      : "=v"(d) : "v"(a), "v"(u), "v"(c));
  return d;
}
__device__ __forceinline__ f2 pk_fma_bl_p(f2 p, f2 v, f2 c) {
  f2 d;
  asm("v_pk_fma_f32 %0, %1, %2, %3 op_sel:[0,0,0] op_sel_hi:[1,0,1]"
      : "=v"(d) : "v"(p), "v"(v), "v"(c));
  return d;
}
__device__ __forceinline__ f2 pk_fma_bl_m(f2 p, f2 v, f2 c) {
  f2 d;
  asm("v_pk_fma_f32 %0, %1, %2, %3 op_sel:[0,0,0] op_sel_hi:[1,0,1] neg_lo:[0,1,0] neg_hi:[0,1,0]"
      : "=v"(d) : "v"(p), "v"(v), "v"(c));
  return d;
}
__device__ __forceinline__ f2 pk_mul_d(f2 a, f2 b) {
  f2 d;
  asm("v_pk_mul_f32 %0, %1, %2" : "=v"(d) : "v"(a), "v"(b));
  return d;
}
__device__ __forceinline__ f2 pk_fma_d(f2 a, f2 b, f2 c) {
  f2 d;
  asm("v_pk_fma_f32 %0, %1, %2, %3" : "=v"(d) : "v"(a), "v"(b), "v"(c));
  return d;
}

template<bool REAL>
__device__ __forceinline__ f2 updp(f2 a, f2 p, f2 u, f2 v) {
  if constexpr (REAL) return pk_fma_bl_p(p, v, pk_mul_bl(a, u));
  else return pk_fma_rot_p(p, v, pk_fma_bl_p(p, v, pk_fma_rot_p(a, u, pk_mul_bl(a, u))));
}
template<bool REAL>
__device__ __forceinline__ f2 updm(f2 a, f2 p, f2 u, f2 v) {
  if constexpr (REAL) return pk_fma_bl_m(p, v, pk_mul_bl(a, u));
  else return pk_fma_rot_p(p, v, pk_fma_bl_m(p, v, pk_fma_rot_m(a, u, pk_mul_bl(a, u))));
}
__device__ __forceinline__ f2 cmul(f2 a, f2 u) { return pk_fma_rot_p(a, u, pk_mul_bl(a, u)); }

// xor-shuffle within a wave (l0 lane gates + reductions)
template<unsigned MLO>
__device__ __forceinline__ float shx(float v, int lane4) {
  if constexpr (MLO == 0u) {
    return v;
  } else if constexpr (MLO < 32u) {
    constexpr int off = (int)((MLO << 10) | 0x1fu);
    return __int_as_float(__builtin_amdgcn_ds_swizzle(__float_as_int(v), off));
  } else {
    int addr = lane4 ^ (int)(MLO << 2);
    return __int_as_float(__builtin_amdgcn_ds_bpermute(addr, __float_as_int(v)));
  }
}

// old 1-element gate (l0 lane gates only; verified r4-r11)
template<unsigned M, unsigned R, bool REAL>
__device__ __forceinline__ void gate1(f2* st, float ghalf, float phihalf, int lane, int lane4) {
  float s, c;
  __sincosf(ghalf, &s, &c);
  constexpr unsigned MLO = M & 63u;
  constexpr unsigned RLO = R & 63u;
  float sL = (__popc((int)(RLO & (unsigned)lane)) & 1) ? -1.f : 1.f;
  f2 u, v;
  float sf, cf;
  __sincosf(phihalf, &sf, &cf);
  u.x = c * cf;         u.y = (-c * sf) * sL;
  v.x = (-s * cf) * sL; v.y = s * sf;
  f2 p;
  p.x = shx<MLO>(st[0].x, lane4);
  p.y = shx<MLO>(st[0].y, lane4);
  st[0] = updp<REAL>(st[0], p, u, v);  // r=0: reg parity 0
}

// coefficient helper
template<unsigned R, bool REAL>
__device__ __forceinline__ void make_uv(float ghalf, float phihalf, int l6, int w, f2& u, f2& v) {
  constexpr unsigned RHI = (R >> 6) & 63u;
  constexpr unsigned RLO = R & 63u;
  constexpr unsigned S5 = (RHI >> 5) & 1u;
  float s, c;
  __sincosf(ghalf, &s, &c);
  int par = __popc((int)(RLO & (unsigned)l6));
  if constexpr (S5 != 0u) par ^= w;
  float sL = (par & 1) ? -1.f : 1.f;
  if constexpr (REAL) {
    u.x = c;       u.y = 0.f;
    v.x = -s * sL; v.y = 0.f;
  } else {
    float sf, cf;
    __sincosf(phihalf, &sf, &cf);
    u.x = c * cf;         u.y = (-c * sf) * sL;
    v.x = (-s * cf) * sL; v.y = s * sf;
  }
}

// reg-local gate on the wave's 32 regs (mask bit5 clear)
template<unsigned M, unsigned R, bool REAL>
__device__ __forceinline__ void gate32_local(f2* st, float ghalf, float phihalf, int l6, int w) {
  constexpr unsigned MHI = (M >> 6) & 31u;
  constexpr unsigned RHI5 = (R >> 6) & 31u;
  static_assert(MHI != 0u, "empty local mask");
  f2 u, v;
  make_uv<R, REAL>(ghalf, phihalf, l6, w, u, v);
  constexpr unsigned TB = MHI & (~MHI + 1u);
  #pragma unroll
  for (int rl = 0; rl < 32; ++rl) {
    if ((rl & (int)TB) == 0) {
      int rl2 = rl ^ (int)MHI;
      const bool rp = ((__builtin_popcount((unsigned)rl & RHI5)) & 1) != 0;
      f2 a = st[rl], b = st[rl2];
      st[rl]  = rp ? updm<REAL>(a, b, u, v) : updp<REAL>(a, b, u, v);
      st[rl2] = rp ? updp<REAL>(b, a, u, v) : updm<REAL>(b, a, u, v);
    }
  }
}

// cross-wave gate (mask bit5 set): 2 batches of 16 pairs through LDS
template<unsigned M, unsigned R, bool REAL>
__device__ __forceinline__ void gate32_cross(f2* st, f2* lds, float ghalf, float phihalf, int l6, int w) {
  constexpr unsigned MHI = (M >> 6) & 63u;
  constexpr unsigned ML5 = MHI & 31u;
  constexpr unsigned RHI5 = (R >> 6) & 31u;
  constexpr int FLIP = (int)((ML5 >> 4) & 1u);
  f2 u, v;
  make_uv<R, REAL>(ghalf, phihalf, l6, w, u, v);
  #pragma unroll
  for (int t = 0; t < 2; ++t) {
    if (w == 0) {
      #pragma unroll
      for (int rr = 0; rr < 16; ++rr) {
        const int rlm = (t << 4) | rr;          // pair index = rlm, slot i = rlm & 15 = rr
        lds[(rr << 6) | l6] = st[rlm];
      }
    } else {
      #pragma unroll
      for (int rr = 0; rr < 16; ++rr) {
        const int rlm = ((t ^ FLIP) << 4) | rr; // bit4(rlm ^ ML5) == t
        const int i = (rlm ^ (int)ML5) & 15;    // pair index low bits
        lds[1024 | (i << 6) | l6] = st[rlm];
      }
    }
    __syncthreads();
    if (w == 0) {
      #pragma unroll
      for (int rr = 0; rr < 16; ++rr) {
        const int rlm = (t << 4) | rr;
        f2 p = lds[1024 | (rr << 6) | l6];
        const bool rp = ((__builtin_popcount((unsigned)rlm & RHI5)) & 1) != 0;
        st[rlm] = rp ? updm<REAL>(st[rlm], p, u, v) : updp<REAL>(st[rlm], p, u, v);
      }
    } else {
      #pragma unroll
      for (int rr = 0; rr < 16; ++rr) {
        const int rlm = ((t ^ FLIP) << 4) | rr;
        const int i = (rlm ^ (int)ML5) & 15;
        f2 p = lds[(i << 6) | l6];
        const bool rp = ((__builtin_popcount((unsigned)rlm & RHI5)) & 1) != 0;
        st[rlm] = rp ? updm<REAL>(st[rlm], p, u, v) : updp<REAL>(st[rlm], p, u, v);
      }
    }
    __syncthreads();
  }
}

// ---- layer 0 (wave0 only; identity labeling) ----
template<int Q>
__device__ __forceinline__ void l0_lane(f2* st, const float* ang, const float* __restrict__ qp, int lane, int lane4) {
  if constexpr (Q < NQ) {
    constexpr unsigned M = PLAN.l0m[Q];
    if constexpr (M < 64u) {
      gate1<M, PLAN.l0r[Q], false>(st, 0.5f * (ang[Q] + qp[Q * 2 + 0]), 0.5f * qp[Q * 2 + 1], lane, lane4);
    }
    l0_lane<Q + 1>(st, ang, qp, lane, lane4);
  }
}
template<int Q, unsigned DONE>
__device__ __forceinline__ void l0_reg32(f2* st, const float* ang, const float* __restrict__ qp) {
  if constexpr (Q < NQ) {
    constexpr unsigned M = PLAN.l0m[Q];
    if constexpr (M >= 64u && ((M >> 6) & 63u) != 32u) {
      constexpr unsigned TB = (M >> 6) & 31u;
      float sh = 0.5f * (ang[Q] + qp[Q * 2 + 0]);
      float ph = 0.5f * qp[Q * 2 + 1];
      float s, c, sf, cf;
      __sincosf(sh, &s, &c);
      __sincosf(ph, &sf, &cf);
      f2 u0; u0.x = c * cf; u0.y = -c * sf;
      f2 u1; u1.x = s * cf; u1.y =  s * sf;
      #pragma unroll
      for (int r = 0; r < 32; ++r) {
        if ((r & ~(int)DONE & 31) == 0) {
          f2 a = st[r];
          int r2 = r | (int)TB;
          st[r]  = cmul(a, u0);
          st[r2] = cmul(a, u1);
        }
      }
      l0_reg32<Q + 1, DONE | TB>(st, ang, qp);
    } else {
      l0_reg32<Q + 1, DONE>(st, ang, qp);
    }
  }
}

// ---- LDS remap (verified r10 formulas; loops partitioned by wave = reg bit 5) ----
__device__ __forceinline__ int pad(int a) { return a + (a >> 5); }

template<int PH>
__device__ __forceinline__ void remap32(f2* st, f2* lds, int l6, int w) {
  constexpr int b = PLAN.cb[PH];
  constexpr unsigned LM = (1u << (6 + b)) - 1u;
  unsigned B = 0;
  #pragma unroll
  for (int j = 0; j < 6; ++j) B ^= (unsigned)(-(int)((l6 >> j) & 1)) & PLAN.phi[PH][j];
  unsigned rBe = (B & LM) | ((B >> 1) & (0x7FFu & ~LM));
  if constexpr (b == 5) {
    #pragma unroll
    for (int s = 0; s < 2; ++s) {
      if (w == s) {
        #pragma unroll
        for (int rl = 0; rl < 32; ++rl) lds[pad((rl << 6) | l6)] = st[rl];
      }
      __syncthreads();
      if (w == s) {
        #pragma unroll
        for (int rl = 0; rl < 32; ++rl) st[rl] = lds[pad((int)(rBe ^ PLAN.coffE[PH][rl | (s << 5)]))];
      }
      __syncthreads();
    }
  } else {
    constexpr unsigned LM5 = (1u << b) - 1u;
    #pragma unroll
    for (int s = 0; s < 2; ++s) {
      if (w == 0) {
        #pragma unroll
        for (int rl = 0; rl < 32; ++rl) {
          if (((rl >> b) & 1) == s) {
            const int cr = (rl & (int)LM5) | ((rl >> 1) & (15 & ~(int)LM5));
            lds[pad((cr << 6) | l6)] = st[rl];
          }
        }
      } else {
        #pragma unroll
        for (int rl = 0; rl < 32; ++rl) {
          if (((rl >> b) & 1) == s) {
            const int cr = 16 | (rl & (int)LM5) | ((rl >> 1) & (15 & ~(int)LM5));
            lds[pad((cr << 6) | l6)] = st[rl];
          }
        }
      }
      __syncthreads();
      if (w == 0) {
        #pragma unroll
        for (int rl = 0; rl < 32; ++rl) {
          if (((rl >> b) & 1) == s) st[rl] = lds[pad((int)(rBe ^ PLAN.coffE[PH][rl]))];
        }
      } else {
        #pragma unroll
        for (int rl = 0; rl < 32; ++rl) {
          if (((rl >> b) & 1) == s) st[rl] = lds[pad((int)(rBe ^ PLAN.coffE[PH][rl | 32]))];
        }
      }
      __syncthreads();
    }
  }
}

template<int PH, int I>
__device__ __forceinline__ void do_phase(f2* st, f2* lds, const float* ang, const float* __restrict__ qp, int l6, int w) {
  if constexpr (I < 6) {
    constexpr int L = 1 + PH / 2;
    constexpr bool REAL = (L == NL - 1);
    constexpr int q = (PH % 2) * 6 + I;
    constexpr unsigned M = PLAN.gm[PH][I];
    constexpr unsigned R = PLAN.gr[PH][I];
    static_assert((M & 63u) == 0u, "phase gate not reg-local");
    float th0 = qp[(L * NQ + q) * 2 + 0];
    float ph1 = REAL ? 0.f : 0.5f * qp[(L * NQ + q) * 2 + 1];
    float g = 0.5f * (ang[q] + th0);
    if constexpr (((M >> 11) & 1u) != 0u)
      gate32_cross<M, R, REAL>(st, lds, g, ph1, l6, w);
    else
      gate32_local<M, R, REAL>(st, g, ph1, l6, w);
    do_phase<PH, I + 1>(st, lds, ang, qp, l6, w);
  }
}

__device__ __forceinline__ float redsum(float v, int lane4) {
  v += shx<1>(v, lane4);
  v += shx<2>(v, lane4);
  v += shx<4>(v, lane4);
  v += shx<8>(v, lane4);
  v += shx<16>(v, lane4);
  v += shx<32>(v, lane4);
  return v;
}
__device__ __forceinline__ float fast_tanh(float x) {
  float e = __expf(2.f * x);
  float r = __builtin_amdgcn_rcpf(e + 1.f);
  return 1.f - 2.f * r;
}

// per-wave partial <Z_q>; wave-bit (storage bit 11) parity applied via w
template<int Q>
__device__ __forceinline__ void finish(const f2* acc6, float& outv, int l6, int lane4, int w) {
  if constexpr (Q < NQ) {
    constexpr unsigned RLO = PLAN.rf[Q] & 63u;
    constexpr unsigned S11 = (PLAN.rf[Q] >> 11) & 1u;
    float a = (Q & 1) ? acc6[Q / 2].y : acc6[Q / 2].x;
    int par = __popc((int)(RLO & (unsigned)l6));
    if constexpr (S11 != 0u) par ^= w;
    float sLn = (par & 1) ? -a : a;
    float t = redsum(sLn, lane4);
    if (l6 == Q) outv = t;
    finish<Q + 1>(acc6, outv, l6, lane4, w);
  }
}

__global__ __launch_bounds__(128) void qtr_kernel(const float* __restrict__ x,
                                                  const float* __restrict__ W,
                                                  const float* __restrict__ qp,
                                                  float* __restrict__ out) {
  __shared__ f2 ldsb[2112];  // 16.5KB (2048 + pad slots for remap)
  int bb = blockIdx.x;
  int tid = threadIdx.x;
  int w = tid >> 6;
  int l6 = tid & 63;
  int lane4 = l6 << 2;

  // angles[q] = pi * tanh(dot(x[b], W[q])) — both waves compute (redundant, cheap)
  float xv = x[bb * FEAT + l6];
  float ang[NQ];
  #pragma unroll
  for (int q = 0; q < NQ; ++q) {
    float prod = redsum(xv * W[q * FEAT + l6], lane4);
    ang[q] = PI_F * fast_tanh(prod);
  }

  f2 st[32];
  if (w == 0) {
    st[0].x = (l6 == 0) ? 1.f : 0.f;
    st[0].y = 0.f;
    l0_lane<0>(st, ang, qp, l6, lane4);
    l0_reg32<0, 0u>(st, ang, qp);
  }
  {  // l0 wave-bit gate (qubit QW, TB=32): wave0 *= U00, wave1 = pre * U10
    float sh = 0.5f * (ang[QW] + qp[QW * 2 + 0]);
    float ph = 0.5f * qp[QW * 2 + 1];
    float s, c, sf, cf;
    __sincosf(sh, &s, &c);
    __sincosf(ph, &sf, &cf);
    f2 u0; u0.x = c * cf; u0.y = -c * sf;
    f2 u1; u1.x = s * cf; u1.y =  s * sf;
    if (w == 0) {
      #pragma unroll
      for (int rl = 0; rl < 32; ++rl) ldsb[(rl << 6) | l6] = st[rl];
    }
    __syncthreads();
    if (w == 0) {
      #pragma unroll
      for (int rl = 0; rl < 32; ++rl) st[rl] = cmul(st[rl], u0);
    } else {
      #pragma unroll
      for (int rl = 0; rl < 32; ++rl) st[rl] = cmul(ldsb[(rl << 6) | l6], u1);
    }
    __syncthreads();
  }

  remap32<0>(st, ldsb, l6, w);
  do_phase<0, 0>(st, ldsb, ang, qp, l6, w);
  remap32<1>(st, ldsb, l6, w);
  do_phase<1, 0>(st, ldsb, ang, qp, l6, w);
  remap32<2>(st, ldsb, l6, w);
  do_phase<2, 0>(st, ldsb, ang, qp, l6, w);
  remap32<3>(st, ldsb, l6, w);
  do_phase<3, 0>(st, ldsb, ang, qp, l6, w);

  // probabilities -> 6 packed parity-signed accumulators (reg bits 6..10; bit 11 in finish)
  f2 acc6[6];
  #pragma unroll
  for (int j = 0; j < 6; ++j) { acc6[j].x = 0.f; acc6[j].y = 0.f; }
  #pragma unroll
  for (int rl = 0; rl < 32; ++rl) {
    f2 q2 = pk_mul_d(st[rl], st[rl]);
    float p = q2.x + q2.y;
    f2 pp; pp.x = p; pp.y = p;
    #pragma unroll
    for (int j = 0; j < 6; ++j) {
      const bool n0 = ((__builtin_popcount(((PLAN.rf[2 * j]     >> 6) & 31u) & (unsigned)rl)) & 1) != 0;
      const bool n1 = ((__builtin_popcount(((PLAN.rf[2 * j + 1] >> 6) & 31u) & (unsigned)rl)) & 1) != 0;
      f2 sg; sg.x = n0 ? -1.f : 1.f; sg.y = n1 ? -1.f : 1.f;
      acc6[j] = pk_fma_d(pp, sg, acc6[j]);
    }
  }

  float outv = 0.f;
  finish<0>(acc6, outv, l6, lane4, w);

  // cross-wave combine (sign already applied per wave in finish)
  float* fl = (float*)ldsb;
  if (l6 < NQ) fl[w * 16 + l6] = outv;
  __syncthreads();
  if (tid < NQ) out[bb * NQ + tid] = fl[tid] + fl[16 + tid];
}

}  // namespace

extern "C" void kernel_launch(void* const* d_in, const int* in_sizes, int n_in,
                              void* d_out, int out_size, void* d_ws, size_t ws_size,
                              hipStream_t stream) {
  const float* x  = (const float*)d_in[0];
  const float* W  = (const float*)d_in[1];
  const float* qp = (const float*)d_in[2];
  float* out = (float*)d_out;
  qtr_kernel<<<8192, 128, 0, stream>>>(x, W, qp, out);
}

// Round 14
// 129.424 us; speedup vs baseline: 1.3803x; 1.3803x over previous
//
#include <hip/hip_runtime.h>

namespace {

constexpr int NQ = 12;
constexpr int NL = 3;
constexpr int FEAT = 64;
constexpr float PI_F = 3.14159265358979323846f;

typedef float f2 __attribute__((ext_vector_type(2)));

// ============================ constexpr GF(2) toolkit ============================
constexpr int par12(unsigned x) { int p = 0; for (int i = 0; i < 12; ++i) p ^= (int)((x >> i) & 1u); return p; }
constexpr int lead12(unsigned x) { for (int k = 11; k >= 0; --k) if ((x >> k) & 1u) return k; return -1; }

struct Ech { unsigned v[16] = {}; int n = 0; };
constexpr unsigned ech_reduce(const Ech& E, unsigned x) {
  for (int i = 0; i < E.n; ++i) { int lb = lead12(E.v[i]); if (lb >= 0 && ((x >> lb) & 1u)) x ^= E.v[i]; }
  return x;
}
constexpr bool ech_add(Ech& E, unsigned x) {
  unsigned r = ech_reduce(E, x);
  if (!r) return false;
  int lb = lead12(r);
  int pos = E.n;
  for (int i = 0; i < E.n; ++i) { if (lead12(E.v[i]) < lb) { pos = i; break; } }
  for (int i = E.n; i > pos; --i) E.v[i] = E.v[i - 1];
  E.v[pos] = r; E.n++;
  return true;
}

constexpr unsigned apmat(const unsigned* rows, unsigned v) {
  unsigned o = 0; for (int k = 0; k < 12; ++k) if (par12(rows[k] & v)) o |= 1u << k; return o;
}
constexpr bool inv12(const unsigned* in, unsigned* out) {
  unsigned a[12] = {}, b[12] = {};
  for (int k = 0; k < 12; ++k) { a[k] = in[k]; b[k] = 1u << k; }
  for (int c = 0; c < 12; ++c) {
    int p = -1;
    for (int r = c; r < 12; ++r) if ((a[r] >> c) & 1u) { p = r; break; }
    if (p < 0) return false;
    unsigned t = a[c]; a[c] = a[p]; a[p] = t; t = b[c]; b[c] = b[p]; b[p] = t;
    for (int r = 0; r < 12; ++r) if (r != c && ((a[r] >> c) & 1u)) { a[r] ^= a[c]; b[r] ^= b[c]; }
  }
  for (int k = 0; k < 12; ++k) out[k] = b[k];
  return true;
}
constexpr unsigned dropb(unsigned x, int t) {  // remove bit t, shift higher bits down (11-bit result)
  unsigned lm = (1u << t) - 1u;
  return (x & lm) | ((x >> 1) & (0x7FFu & ~lm));
}

// ============ logical circuit tracking (deferred CNOT ring, verified r1-r13) ============
struct Logical {
  unsigned m[NL][NQ] = {}, rv[NL][NQ] = {}, rf[NQ] = {};
  bool ok = false;
};
constexpr Logical compute_raw() {
  Logical mp{};
  unsigned col[NQ] = {}, row[NQ] = {};
  for (int b = 0; b < NQ; ++b) { col[b] = 1u << b; row[b] = 1u << b; }
  mp.ok = true;
  for (int L = 0; L < NL; ++L) {
    for (int q = 0; q < NQ; ++q) {
      mp.m[L][q]  = col[NQ - 1 - q];
      mp.rv[L][q] = row[NQ - 1 - q];
      if (par12(mp.m[L][q] & mp.rv[L][q]) != 1) mp.ok = false;
    }
    for (int q = 0; q < NQ; ++q) {
      int bc = NQ - 1 - q;
      int bt = NQ - 1 - ((q + 1) % NQ);
      col[bc] ^= col[bt];
      row[bt] ^= row[bc];
    }
  }
  for (int q = 0; q < NQ; ++q) mp.rf[q] = row[NQ - 1 - q];
  return mp;
}

// ============================ phase/remap plan (VERIFIED r10/r11) ============================
struct Plan {
  unsigned l0m[NQ] = {}, l0r[NQ] = {};
  unsigned gm[4][6] = {};
  unsigned gr[4][6] = {};
  unsigned rf[NQ] = {};
  unsigned phi[4][6] = {};
  unsigned coffE[4][64] = {};
  int cb[4] = {};
  bool ok = false;
};

constexpr bool findH(const Ech& G, unsigned rho, unsigned& out) {
  for (unsigned t = 0; t < 12; ++t) {
    unsigned v = 1u << t;
    if (par12(v & rho) == 0 && ech_reduce(G, v)) { out = v; return true; }
  }
  for (unsigned v = 1; v < 4096u; ++v) {
    if (par12(v & rho) == 0 && ech_reduce(G, v)) { out = v; return true; }
  }
  return false;
}

constexpr Plan build_plan() {
  Logical raw = compute_raw();
  Plan P{};
  P.ok = raw.ok;
  for (int q = 0; q < NQ; ++q) { P.l0m[q] = raw.m[0][q]; P.l0r[q] = raw.rv[0][q]; }
  unsigned fwd[12] = {}, invc[12] = {};
  for (int k = 0; k < 12; ++k) { fwd[k] = 1u << k; invc[k] = 1u << k; }
  for (int ph = 0; ph < 4; ++ph) {
    const int L = 1 + ph / 2, q0 = (ph % 2) * 6;
    unsigned ml[6] = {};
    for (int i = 0; i < 6; ++i) ml[i] = raw.m[L][q0 + i];
    bool done = false;
    for (int cbi = 5; cbi >= 0 && !done; --cbi) {
      unsigned rho = fwd[6 + cbi];
      bool bad = false;
      int idx = -1;
      for (int i = 0; i < 6; ++i) if (par12(ml[i] & rho)) { idx = i; break; }
      unsigned uc = 0;
      Ech W{};
      if (idx >= 0) {
        uc = ml[idx];
        for (int i = 0; i < 6; ++i) {
          if (i == idx) continue;
          unsigned w = par12(ml[i] & rho) ? (ml[i] ^ uc) : ml[i];
          ech_add(W, w);
        }
        if (W.n > 5) bad = true;
      } else {
        for (int i = 0; i < 6; ++i) ech_add(W, ml[i]);
        if (W.n > 5) bad = true;
        if (!bad) {
          bool got = false;
          for (unsigned t = 0; t < 12 && !got; ++t) {
            unsigned v = 1u << t;
            if (par12(v & rho)) { uc = v; got = true; }
          }
          if (!got) bad = true;
        }
      }
      if (bad) continue;
      Ech G{};
      for (int i = 0; i < W.n && !bad; ++i) if (!ech_add(G, W.v[i])) bad = true;
      if (!bad && !ech_add(G, uc)) bad = true;
      if (bad) continue;
      unsigned regH[5] = {};
      int nH = W.n;
      for (int i = 0; i < nH; ++i) regH[i] = W.v[i];
      for (int slot = nH; slot < 5 && !bad; ++slot) {
        unsigned v = 0;
        if (!findH(G, rho, v)) { bad = true; break; }
        regH[slot] = v; ech_add(G, v);
      }
      if (bad) continue;
      unsigned lam[6] = {};
      for (int j = 0; j < 6 && !bad; ++j) {
        unsigned cand = invc[j];
        if (par12(cand & rho) != 0 || !ech_reduce(G, cand)) {
          if (!findH(G, rho, cand)) { bad = true; break; }
        }
        lam[j] = cand; ech_add(G, cand);
      }
      if (bad) continue;
      unsigned ncols[12] = {};
      for (int j = 0; j < 6; ++j) ncols[j] = lam[j];
      {
        int w = 0;
        for (int k = 0; k < 6; ++k) ncols[6 + k] = (k == cbi) ? uc : regH[w++];
      }
      unsigned Mrows[12] = {};
      for (int k = 0; k < 12; ++k) {
        unsigned r = 0;
        for (int j = 0; j < 12; ++j) r |= ((ncols[j] >> k) & 1u) << j;
        Mrows[k] = r;
      }
      unsigned fnew[12] = {};
      if (!inv12(Mrows, fnew)) continue;
      bool okp = true;
      unsigned gmv[6] = {}, grv[6] = {};
      for (int i = 0; i < 6 && okp; ++i) {
        unsigned SM = apmat(fnew, ml[i]);
        if (SM & 63u) okp = false;
        unsigned sg = 0;
        for (int k = 0; k < 12; ++k) if (par12(raw.rv[L][q0 + i] & ncols[k])) sg |= 1u << k;
        if (par12(SM & sg) != 1) okp = false;
        gmv[i] = SM; grv[i] = sg;
      }
      unsigned phj[6] = {}, Ust[6] = {};
      for (int j = 0; j < 6 && okp; ++j) {
        phj[j] = apmat(fwd, lam[j]);
        if ((phj[j] >> (6 + cbi)) & 1u) okp = false;
      }
      for (int k = 0; k < 6 && okp; ++k) {
        Ust[k] = apmat(fwd, ncols[6 + k]);
        if (((Ust[k] >> (6 + cbi)) & 1u) != (unsigned)(k == cbi ? 1 : 0)) okp = false;
      }
      if (!okp) continue;
      P.cb[ph] = cbi;
      for (int j = 0; j < 6; ++j) P.phi[ph][j] = phj[j];
      for (int rp = 0; rp < 64; ++rp) {
        unsigned psi = 0;
        for (int i = 0; i < 6; ++i) if ((rp >> i) & 1) psi ^= Ust[i];
        P.coffE[ph][rp] = dropb(psi, 6 + cbi);
      }
      for (int i = 0; i < 6; ++i) { P.gm[ph][i] = gmv[i]; P.gr[ph][i] = grv[i]; }
      for (int k = 0; k < 12; ++k) { fwd[k] = fnew[k]; invc[k] = ncols[k]; }
      done = true;
    }
    if (!done) { P.ok = false; return P; }
  }
  for (int q = 0; q < NQ; ++q) {
    unsigned sg = 0;
    for (int k = 0; k < 12; ++k) if (par12(raw.rf[q] & invc[k])) sg |= 1u << k;
    P.rf[q] = sg;
  }
  return P;
}

constexpr Plan PLAN = build_plan();
static_assert(PLAN.ok, "plan construction failed");

// ============================ packed math in plain C++ ============================
// No inline asm: "v" constraints forced VGPR residency at every use, producing
// ~9k v_accvgpr_read/write per wave when the allocator parked st[] in AGPRs
// (r10-r13 PMC). Plain v2f32 mul/fma selects v_pk_mul_f32/v_pk_fma_f32 with AV
// register classes -> VALU reads/writes AGPR-resident state directly, no shuttles.
// Rotation negations fold into per-gate coefficient VECTORS (hoisted).
__device__ __forceinline__ f2 shuf(f2 a) { return __builtin_shufflevector(a, a, 1, 0); }

// o = {ar*a.x - ai*a.y + br*p.x - bi*p.y,  ar*a.y + ai*a.x + br*p.y + bi*p.x}
// arr={ar,ar}; aii={-ai,+ai}; brr={br,br}; bii={-bi,+bi}
template<bool REAL>
__device__ __forceinline__ f2 updv(f2 a, f2 p, f2 arr, f2 aii, f2 brr, f2 bii) {
  f2 t = a * arr;
  if constexpr (!REAL) t = shuf(a) * aii + t;
  t = p * brr + t;
  if constexpr (!REAL) t = shuf(p) * bii + t;
  return t;
}
// complex multiply o = a * u, urr={u.x,u.x}, uri={-u.y,+u.y}
__device__ __forceinline__ f2 cmulv(f2 a, f2 urr, f2 uri) {
  return shuf(a) * uri + a * urr;
}

// xor-shuffle (remaining uses: l0 lane gates + reductions)
template<unsigned MLO>
__device__ __forceinline__ float shx(float v, int lane4) {
  if constexpr (MLO == 0u) {
    return v;
  } else if constexpr (MLO < 32u) {
    constexpr int off = (int)((MLO << 10) | 0x1fu);
    return __int_as_float(__builtin_amdgcn_ds_swizzle(__float_as_int(v), off));
  } else {
    int addr = lane4 ^ (int)(MLO << 2);
    return __int_as_float(__builtin_amdgcn_ds_bpermute(addr, __float_as_int(v)));
  }
}

// Fused U = RZ(2*phihalf) * RY(2*ghalf); REAL drops RZ (last layer, phases cancel in |amp|^2).
template<unsigned M, unsigned R, int NREG, bool REAL>
__device__ __forceinline__ void gate(f2* st, float ghalf, float phihalf, int lane, int lane4) {
  float s, c;
  __sincosf(ghalf, &s, &c);
  constexpr unsigned MHI = (M >> 6) & 63u;
  constexpr unsigned MLO = M & 63u;
  constexpr unsigned RHI = (R >> 6) & 63u;
  constexpr unsigned RLO = R & 63u;
  float sL = (__popc((int)(RLO & (unsigned)lane)) & 1) ? -1.f : 1.f;
  float ar, aiS, brS, b0i;
  if constexpr (REAL) {
    ar = c; aiS = 0.f; brS = -s * sL; b0i = 0.f;
  } else {
    float sf, cf;
    __sincosf(phihalf, &sf, &cf);
    ar = c * cf; aiS = (-c * sf) * sL; brS = (-s * cf) * sL; b0i = s * sf;
  }
  f2 arr; arr.x = ar; arr.y = ar;
  f2 aip; aip.x = -aiS; aip.y = aiS;
  f2 aim; aim.x = aiS;  aim.y = -aiS;
  f2 brp; brp.x = brS;  brp.y = brS;
  f2 brm; brm.x = -brS; brm.y = -brS;
  f2 bii; bii.x = -b0i; bii.y = b0i;
  if constexpr (MLO == 0u) {
    constexpr unsigned TB = MHI & (~MHI + 1u);
    #pragma unroll
    for (int r = 0; r < NREG; ++r) {
      if ((r & (int)TB) == 0) {
        int r2 = r ^ (int)MHI;
        const bool rp = ((__builtin_popcount((unsigned)r & RHI)) & 1) != 0;
        f2 a = st[r], b = st[r2];
        st[r]  = rp ? updv<REAL>(a, b, arr, aim, brm, bii) : updv<REAL>(a, b, arr, aip, brp, bii);
        st[r2] = rp ? updv<REAL>(b, a, arr, aip, brp, bii) : updv<REAL>(b, a, arr, aim, brm, bii);
      }
    }
  } else {
    #pragma unroll
    for (int r = 0; r < NREG; ++r) {
      f2 p;
      p.x = shx<MLO>(st[r].x, lane4);
      p.y = shx<MLO>(st[r].y, lane4);
      const bool rp = ((__builtin_popcount((unsigned)r & RHI)) & 1) != 0;
      st[r] = rp ? updv<REAL>(st[r], p, arr, aim, brm, bii) : updv<REAL>(st[r], p, arr, aip, brp, bii);
    }
  }
}

// ---- layer 0 on sparse |0..0> (identity labeling; all masks single-bit) ----
template<int Q>
__device__ __forceinline__ void l0_lane(f2* st, const float* ang, const float* __restrict__ qp, int lane, int lane4) {
  if constexpr (Q < NQ) {
    constexpr unsigned M = PLAN.l0m[Q];
    if constexpr (M < 64u) {
      gate<M, PLAN.l0r[Q], 1, false>(st, 0.5f * (ang[Q] + qp[Q * 2 + 0]), 0.5f * qp[Q * 2 + 1], lane, lane4);
    }
    l0_lane<Q + 1>(st, ang, qp, lane, lane4);
  }
}
template<int Q, unsigned DONE>
__device__ __forceinline__ void l0_reg(f2* st, const float* ang, const float* __restrict__ qp) {
  if constexpr (Q < NQ) {
    constexpr unsigned M = PLAN.l0m[Q];
    if constexpr (M >= 64u) {
      constexpr unsigned TB = (M >> 6) & 63u;
      float sh = 0.5f * (ang[Q] + qp[Q * 2 + 0]);
      float ph = 0.5f * qp[Q * 2 + 1];
      float s, c, sf, cf;
      __sincosf(sh, &s, &c);
      __sincosf(ph, &sf, &cf);
      // U00 = c e^{-i phi}: urr={c*cf, c*cf}, uri={-(-c*sf), (-c*sf)} = {c*sf, -c*sf}
      f2 u0r; u0r.x = c * cf;  u0r.y = c * cf;
      f2 u0i; u0i.x = c * sf;  u0i.y = -c * sf;
      // U10 = s e^{+i phi}
      f2 u1r; u1r.x = s * cf;  u1r.y = s * cf;
      f2 u1i; u1i.x = -s * sf; u1i.y = s * sf;
      #pragma unroll
      for (int r = 0; r < 64; ++r) {
        if ((r & ~(int)DONE & 63) == 0) {
          f2 a = st[r];
          int r2 = r | (int)TB;
          st[r]  = cmulv(a, u0r, u0i);
          st[r2] = cmulv(a, u1r, u1i);
        }
      }
      l0_reg<Q + 1, DONE | TB>(st, ang, qp);
    } else {
      l0_reg<Q + 1, DONE>(st, ang, qp);
    }
  }
}

// ---- LDS remap: relabel storage (2 stages x 16KB, wave-local, no barriers) ----
// PAD(a) = a + (a>>5): skewed indexing — injective on [0,2048), applied identically to
// writes and reads (same LDS-slot permutation, correctness invariant).
__device__ __forceinline__ int pad(int a) { return a + (a >> 5); }

template<int PH>
__device__ __forceinline__ void remap(f2* st, f2* lds, int lane) {
  constexpr int b = PLAN.cb[PH];
  constexpr unsigned LM6 = (1u << b) - 1u;
  constexpr unsigned LM = (1u << (6 + b)) - 1u;
  unsigned B = 0;
  #pragma unroll
  for (int j = 0; j < 6; ++j) B ^= (unsigned)(-(int)((lane >> j) & 1)) & PLAN.phi[PH][j];
  unsigned rBe = (B & LM) | ((B >> 1) & (0x7FFu & ~LM));
  #pragma unroll
  for (int s = 0; s < 2; ++s) {
    #pragma unroll
    for (int r = 0; r < 64; ++r) {
      if (((r >> b) & 1) == s) {
        const int cr = (r & (int)LM6) | ((r >> 1) & (31 & ~(int)LM6));
        lds[pad((cr << 6) | lane)] = st[r];
      }
    }
    asm volatile("s_waitcnt lgkmcnt(0)" ::: "memory");
    #pragma unroll
    for (int rp = 0; rp < 64; ++rp) {
      if (((rp >> b) & 1) == s) {
        st[rp] = lds[pad((int)(rBe ^ PLAN.coffE[PH][rp]))];
      }
    }
    asm volatile("s_waitcnt lgkmcnt(0)" ::: "memory");
  }
}

template<int PH, int I>
__device__ __forceinline__ void do_phase(f2* st, const float* ang, const float* __restrict__ qp, int lane, int lane4) {
  if constexpr (I < 6) {
    constexpr int L = 1 + PH / 2;
    constexpr bool REAL = (L == NL - 1);
    constexpr int q = (PH % 2) * 6 + I;
    constexpr unsigned M = PLAN.gm[PH][I];
    constexpr unsigned R = PLAN.gr[PH][I];
    float th0 = qp[(L * NQ + q) * 2 + 0];
    float ph1 = REAL ? 0.f : 0.5f * qp[(L * NQ + q) * 2 + 1];
    gate<M, R, 64, REAL>(st, 0.5f * (ang[q] + th0), ph1, lane, lane4);
    do_phase<PH, I + 1>(st, ang, qp, lane, lane4);
  }
}

__device__ __forceinline__ float redsum(float v, int lane4) {
  v += shx<1>(v, lane4);
  v += shx<2>(v, lane4);
  v += shx<4>(v, lane4);
  v += shx<8>(v, lane4);
  v += shx<16>(v, lane4);
  v += shx<32>(v, lane4);
  return v;
}
__device__ __forceinline__ float fast_tanh(float x) {
  float e = __expf(2.f * x);
  float r = __builtin_amdgcn_rcpf(e + 1.f);
  return 1.f - 2.f * r;
}

template<int Q>
__device__ __forceinline__ void finish(const f2* acc6, float& outv, int lane, int lane4) {
  if constexpr (Q < NQ) {
    constexpr unsigned RLO = PLAN.rf[Q] & 63u;
    float a = (Q & 1) ? acc6[Q / 2].y : acc6[Q / 2].x;
    float sLn = (__popc((int)(RLO & (unsigned)lane)) & 1) ? -a : a;
    float t = redsum(sLn, lane4);
    if (lane == Q) outv = t;
    finish<Q + 1>(acc6, outv, lane, lane4);
  }
}

__global__ __launch_bounds__(64, 2) void qtr_kernel(const float* __restrict__ x,
                                                    const float* __restrict__ W,
                                                    const float* __restrict__ qp,
                                                    float* __restrict__ out) {
  __shared__ f2 ldsb[2112];  // 16.5KB (2048 + 64 pad slots)
  int b = blockIdx.x;
  int lane = threadIdx.x;
  int lane4 = lane << 2;

  // angles[q] = pi * tanh(dot(x[b], W[q]))
  float xv = x[b * FEAT + lane];
  float ang[NQ];
  #pragma unroll
  for (int q = 0; q < NQ; ++q) {
    float prod = redsum(xv * W[q * FEAT + lane], lane4);
    ang[q] = PI_F * fast_tanh(prod);
  }

  // sparse |0..0>
  f2 st[64];
  st[0].x = (lane == 0) ? 1.f : 0.f;
  st[0].y = 0.f;

  l0_lane<0>(st, ang, qp, lane, lane4);
  l0_reg<0, 0u>(st, ang, qp);

  remap<0>(st, ldsb, lane);
  do_phase<0, 0>(st, ang, qp, lane, lane4);
  remap<1>(st, ldsb, lane);
  do_phase<1, 0>(st, ang, qp, lane, lane4);
  remap<2>(st, ldsb, lane);
  do_phase<2, 0>(st, ang, qp, lane, lane4);
  remap<3>(st, ldsb, lane);
  do_phase<3, 0>(st, ang, qp, lane, lane4);

  // probabilities -> 6 packed parity-signed accumulators
  f2 acc6[6];
  #pragma unroll
  for (int j = 0; j < 6; ++j) { acc6[j].x = 0.f; acc6[j].y = 0.f; }
  #pragma unroll
  for (int r = 0; r < 64; ++r) {
    f2 q2 = st[r] * st[r];
    float p = q2.x + q2.y;
    f2 pp; pp.x = p; pp.y = p;
    #pragma unroll
    for (int j = 0; j < 6; ++j) {
      const bool n0 = ((__builtin_popcount(((PLAN.rf[2 * j]     >> 6) & 63u) & (unsigned)r)) & 1) != 0;
      const bool n1 = ((__builtin_popcount(((PLAN.rf[2 * j + 1] >> 6) & 63u) & (unsigned)r)) & 1) != 0;
      f2 sg; sg.x = n0 ? -1.f : 1.f; sg.y = n1 ? -1.f : 1.f;
      acc6[j] = pp * sg + acc6[j];
    }
  }

  float outv = 0.f;
  finish<0>(acc6, outv, lane, lane4);

  if (lane < NQ) out[b * NQ + lane] = outv;
}

}  // namespace

extern "C" void kernel_launch(void* const* d_in, const int* in_sizes, int n_in,
                              void* d_out, int out_size, void* d_ws, size_t ws_size,
                              hipStream_t stream) {
  const float* x  = (const float*)d_in[0];
  const float* W  = (const float*)d_in[1];
  const float* qp = (const float*)d_in[2];
  float* out = (float*)d_out;
  qtr_kernel<<<8192, 64, 0, stream>>>(x, W, qp, out);
}